// Round 12
// baseline (84.744 us; speedup 1.0000x reference)
//
#include <hip/hip_runtime.h>

#define H 512
#define W 512
#define NIMG 8
#define NBAND 32
#define BROWS 16                  // rows per band (NBAND*BROWS == H)

#define PS 576                    // padded SAT stride (PADX=31 + 513 + 32)
#define PP (PS * PS)
#define PADY 32                   // P row p = SAT row y' + 32
#define PADX 31                   // P col c = SAT col x' + 31  (keeps f4 alignment)

#define TSTR 648                  // LDS tile stride (floats) >= phi(575)+4
#define NBLK 2048                 // k_main grid size

typedef float f4 __attribute__((ext_vector_type(4), aligned(4)));
typedef float f2 __attribute__((ext_vector_type(2), aligned(4)));

__device__ __forceinline__ int phi(int c) { return c + 4 * (c >> 5); }  // bank spread

__device__ __forceinline__ f4 ld4(const float* p) {
    return *reinterpret_cast<const f4*>(p);
}

// zero-padded global load ('SAME' conv padding)
__device__ __forceinline__ float ldz(const float* __restrict__ p, int y, int x) {
    return ((unsigned)y < (unsigned)H && (unsigned)x < (unsigned)W) ? p[y * W + x] : 0.0f;
}

// load window [x0-1, x0+8] of row `row` (zero-padded), x0 = 8*lane
__device__ __forceinline__ void loadrow(const float* __restrict__ src, int row,
                                        int x0, int lane, float w[10]) {
    f4 a = {0.f, 0.f, 0.f, 0.f}, b = {0.f, 0.f, 0.f, 0.f};
    if ((unsigned)row < (unsigned)H) {
        const float* p = src + (size_t)row * W + x0;
        a = ld4(p);
        b = ld4(p + 4);
    }
    float left = __shfl_up(b[3], 1, 64);
    if (lane == 0) left = 0.f;
    float right = __shfl_down(a[0], 1, 64);
    if (lane == 63) right = 0.f;
    w[0] = left;
    w[1] = a[0]; w[2] = a[1]; w[3] = a[2]; w[4] = a[3];
    w[5] = b[0]; w[6] = b[1]; w[7] = b[2]; w[8] = b[3];
    w[9] = right;
}

// ---- kernel 1: energy + row prefix -> padded P rows + per-band col sums --
__global__ __launch_bounds__(512) void k_rowband(const float* __restrict__ v,
                                                 const float* __restrict__ i_,
                                                 float* __restrict__ P,
                                                 float* __restrict__ bandsum) {
    const int bid = blockIdx.x;
    const int n = bid & 7;
    const int t = bid >> 3;
    const int m = t & 1;
    const int b = t >> 1;                      // 0..31
    const int map = n * 2 + m;
    const float* src = (m == 0 ? v : i_) + (size_t)n * (H * W);
    float* Pm = P + (size_t)map * PP;

    __shared__ float tile[BROWS][TSTR];        // 41.5 KB

    const int tid = threadIdx.x;
    const int lane = tid & 63, wv = tid >> 6;  // wv 0..7
    const int x0 = lane * 8;

    // band-0 blocks also zero P rows 0..32 (top pad + SAT row 0)
    if (b == 0) {
        const f4 z = {0.f, 0.f, 0.f, 0.f};
        for (int s = tid; s < 33 * (PS / 4); s += 512) {
            int j = s / (PS / 4), c4 = s - j * (PS / 4);
            *reinterpret_cast<f4*>(Pm + (size_t)j * PS + 4 * c4) = z;
        }
    }

    #pragma unroll
    for (int k = 0; k < 2; ++k) {
        const int j = k * 8 + wv;              // row within band, 0..15
        const int y = b * BROWS + j;           // image row
        float w0[10], w1[10], w2[10];
        loadrow(src, y - 1, x0, lane, w0);
        loadrow(src, y,     x0, lane, w1);
        loadrow(src, y + 1, x0, lane, w2);
        float e[8];
        #pragma unroll
        for (int q = 0; q < 8; ++q) {
            float gx = (w0[q + 2] - w0[q]) + 2.0f * (w1[q + 2] - w1[q]) + (w2[q + 2] - w2[q]);
            float gy = (w2[q] - w0[q]) + 2.0f * (w2[q + 1] - w0[q + 1]) + (w2[q + 2] - w0[q + 2]);
            e[q] = gx * gx + gy * gy;
        }
        #pragma unroll
        for (int q = 1; q < 8; ++q) e[q] += e[q - 1];   // in-lane prefix
        const float tot = e[7];
        float s = tot;                                   // wave scan of lane totals
        #pragma unroll
        for (int off = 1; off < 64; off <<= 1) {
            float t2 = __shfl_up(s, off, 64);
            if (lane >= off) s += t2;
        }
        const float excl = s - tot;
        const int pc = phi(32 + x0);           // contiguous for q=0..7 (within 32-block)
        #pragma unroll
        for (int q = 0; q < 8; ++q) tile[j][pc + q] = e[q] + excl;
    }
    __syncthreads();

    // pads in LDS: left cols 0..31 = 0 (SAT col <= 0); right cols 544..575 = col 543
    {
        const int j = tid >> 5, c = tid & 31;  // 16 rows x 32 cols = 512 threads
        tile[j][phi(c)] = 0.f;
        tile[j][phi(544 + c)] = tile[j][phi(543)];
    }
    __syncthreads();

    // per-band column sums (incl. pad cols) for the column-accumulate pass
    float* bs = bandsum + ((size_t)map * NBAND + b) * PS;
    for (int c = tid; c < PS; c += 512) {
        float s = 0.f;
        #pragma unroll
        for (int j = 0; j < BROWS; ++j) s += tile[j][phi(c)];
        bs[c] = s;
    }

    // coalesced padded row-prefix writeout: P rows 33+16b .. 48+16b
    for (int s4 = tid; s4 < BROWS * (PS / 4); s4 += 512) {
        int j = s4 / (PS / 4), c4 = s4 - j * (PS / 4);
        f4 val = *reinterpret_cast<const f4*>(&tile[j][phi(4 * c4)]);
        *reinterpret_cast<f4*>(Pm + (size_t)(PADY + 1 + b * BROWS + j) * PS + 4 * c4) = val;
    }
}

// ---- kernel 2: in-place column accumulate on P (band offsets inline) -----
// Left-pad cols 0..30 stay zero under accumulation -> skipped.
// Two-phase load-then-store so the 16 row loads pipeline.
__global__ __launch_bounds__(576) void k_colapply(float* __restrict__ P,
                                                  const float* __restrict__ bandsum) {
    const int bid = blockIdx.x;
    const int n = bid & 7;
    const int t = bid >> 3;
    const int m = t & 1;
    const int b = t >> 1;
    const int map = n * 2 + m;
    const int c = threadIdx.x;                 // 0..575 (one P column)
    if (c < PADX) return;                      // left pad: already zero
    const float* bs = bandsum + (size_t)map * NBAND * PS + c;
    float run = 0.f;
    for (int bb = 0; bb < b; ++bb) run += bs[(size_t)bb * PS];
    float* Pr = P + (size_t)map * PP + (size_t)(PADY + 1 + b * BROWS) * PS + c;
    float vals[BROWS];
    #pragma unroll
    for (int j = 0; j < BROWS; ++j) vals[j] = Pr[(size_t)j * PS];
    #pragma unroll
    for (int j = 0; j < BROWS; ++j) {
        run += vals[j];
        Pr[(size_t)j * PS] = run;
    }
    if (b == NBAND - 1) {                      // bottom pad rows 545..575 = SAT row 512
        float* Pp = P + (size_t)map * PP + (size_t)(PADY + 1 + H) * PS + c;
        #pragma unroll
        for (int j = 0; j < PS - (PADY + 1 + H); ++j)
            Pp[(size_t)j * PS] = run;
    }
}

// ---- sobel for 4 consecutive pixels (vectorized fast path) ---------------
__device__ __forceinline__ void sobel4(const float* __restrict__ p, int y, int x4,
                                       bool fast, float gx[4], float gy[4]) {
    float r0[6], r1[6], r2[6];
    if (fast) {
        const float* a = p + (size_t)(y - 1) * W + (x4 - 1);
        f4 A = ld4(a);             f2 Ab = *reinterpret_cast<const f2*>(a + 4);
        f4 Bv = ld4(a + W);        f2 Bb = *reinterpret_cast<const f2*>(a + W + 4);
        f4 Cv = ld4(a + 2 * W);    f2 Cb = *reinterpret_cast<const f2*>(a + 2 * W + 4);
        r0[0]=A[0];  r0[1]=A[1];  r0[2]=A[2];  r0[3]=A[3];  r0[4]=Ab[0]; r0[5]=Ab[1];
        r1[0]=Bv[0]; r1[1]=Bv[1]; r1[2]=Bv[2]; r1[3]=Bv[3]; r1[4]=Bb[0]; r1[5]=Bb[1];
        r2[0]=Cv[0]; r2[1]=Cv[1]; r2[2]=Cv[2]; r2[3]=Cv[3]; r2[4]=Cb[0]; r2[5]=Cb[1];
    } else {
        #pragma unroll
        for (int q = 0; q < 6; ++q) {
            r0[q] = ldz(p, y - 1, x4 - 1 + q);
            r1[q] = ldz(p, y,     x4 - 1 + q);
            r2[q] = ldz(p, y + 1, x4 - 1 + q);
        }
    }
    #pragma unroll
    for (int q = 0; q < 4; ++q) {
        gx[q] = (r0[q + 2] - r0[q]) + 2.0f * (r1[q + 2] - r1[q]) + (r2[q + 2] - r2[q]);
        gy[q] = (r2[q] - r0[q]) + 2.0f * (r2[q + 1] - r0[q + 1]) + (r2[q + 2] - r0[q + 2]);
    }
}

// ---- kernel 3: fused sobel + clamp-free f4 SAT gather + residual ---------
// Lane remap (col = tid>>3): edge columns land in 1 of 4 waves per block
// instead of all 4 -> slow-path divergence fraction ~0.51 -> ~0.15.
__global__ __launch_bounds__(256) void k_main(const float* __restrict__ v,
                                              const float* __restrict__ i_,
                                              const float* __restrict__ img,
                                              const float* __restrict__ P,
                                              double* __restrict__ partials) {
    const int bid = blockIdx.x;
    const int n = bid & 7;                     // image -> XCD pin
    const int t = bid >> 3;                    // 0..255
    const int tx = t & 3, ty = t >> 2;         // tile: 128 wide x 8 rows
    const int col = threadIdx.x >> 3;          // 0..31 (col-group)
    const int row = threadIdx.x & 7;           // 0..7
    const int x4 = tx * 128 + col * 4;
    const int y  = ty * 8 + row;

    const float* pv = v   + (size_t)n * (H * W);
    const float* pi = i_  + (size_t)n * (H * W);
    const float* pf = img + (size_t)n * (H * W);
    const float* Pv = P + (size_t)(n * 2 + 0) * PP;
    const float* Pi = P + (size_t)(n * 2 + 1) * PP;

    float gvx[4], gvy[4], gix[4], giy[4], gfx[4], gfy[4];
    const bool fast = (y >= 1 && y <= H - 2 && x4 >= 4 && x4 <= W - 8);
    sobel4(pv, y, x4, fast, gvx, gvy);
    sobel4(pi, y, x4, fast, gix, giy);
    sobel4(pf, y, x4, fast, gfx, gfy);

    float dvx[4], dvy[4], rx[4], ry[4];
    #pragma unroll
    for (int q = 0; q < 4; ++q) {
        dvx[q] = gvx[q] - gix[q];
        dvy[q] = gvy[q] - giy[q];
        rx[q]  = gfx[q] - gix[q];
        ry[q]  = gfy[q] - giy[q];
    }

    const int   radii[5] = {1, 3, 7, 15, 30};
    // wt = sv / (sv + si + eps*w^2)  (identical algebra to reference)
    const float epsw[5]  = {9e-8f, 4.9e-7f, 2.25e-6f, 9.61e-6f, 3.721e-5f};

    float acc = 0.0f;
    #pragma unroll
    for (int k = 0; k < 5; ++k) {
        const int r = radii[k];
        const size_t ro0 = (size_t)(y - r + PADY) * PS;
        const size_t ro1 = (size_t)(y + r + 1 + PADY) * PS;
        const int x0 = x4 - r + PADX;
        const int x1 = x4 + r + 1 + PADX;
        f4 sa = ld4(Pv + ro1 + x1), sb = ld4(Pv + ro0 + x1);
        f4 sc = ld4(Pv + ro1 + x0), sd = ld4(Pv + ro0 + x0);
        f4 ua = ld4(Pi + ro1 + x1), ub = ld4(Pi + ro0 + x1);
        f4 uc = ld4(Pi + ro1 + x0), ud = ld4(Pi + ro0 + x0);
        f4 sv = sa - sb - sc + sd;
        f4 si = ua - ub - uc + ud;
        #pragma unroll
        for (int q = 0; q < 4; ++q) {
            float d  = sv[q] + si[q] + epsw[k];
            float wt = sv[q] * __builtin_amdgcn_rcpf(d);
            float dx = rx[q] - wt * dvx[q];
            float dy = ry[q] - wt * dvy[q];
            acc += dx * dx + dy * dy;
        }
    }

    // block reduction (f64, deterministic)
    double a = (double)acc;
    const int lane = threadIdx.x & 63, wid = threadIdx.x >> 6;
    #pragma unroll
    for (int off = 32; off > 0; off >>= 1) a += __shfl_down(a, off, 64);
    __shared__ double red[4];
    if (lane == 0) red[wid] = a;
    __syncthreads();
    if (threadIdx.x == 0)
        partials[bid] = red[0] + red[1] + red[2] + red[3];
}

// ---- kernel 4: final reduce ----------------------------------------------
__global__ __launch_bounds__(256) void k_reduce(const double* __restrict__ partials,
                                                int np, float* __restrict__ out) {
    __shared__ double red[256];
    double s = 0.0;
    for (int idx = threadIdx.x; idx < np; idx += 256) s += partials[idx];
    red[threadIdx.x] = s;
    __syncthreads();
    #pragma unroll
    for (int t = 128; t > 0; t >>= 1) {
        if (threadIdx.x < t) red[threadIdx.x] += red[threadIdx.x + t];
        __syncthreads();
    }
    if (threadIdx.x == 0)
        out[0] = (float)(red[0] / (double)((size_t)NIMG * H * W));
}

// ---- launch --------------------------------------------------------------

extern "C" void kernel_launch(void* const* d_in, const int* in_sizes, int n_in,
                              void* d_out, int out_size, void* d_ws, size_t ws_size,
                              hipStream_t stream) {
    const float* v   = (const float*)d_in[0];
    const float* i_  = (const float*)d_in[1];
    const float* img = (const float*)d_in[2];
    float* out = (float*)d_out;

    float* P         = (float*)d_ws;                               // 16 * 576*576 f32 = 21.2 MB
    float* bandsum   = P + (size_t)16 * PP;                        // 16 * 32 * 576 f32 = 1.2 MB
    double* partials = (double*)(bandsum + (size_t)16 * NBAND * PS);  // 2048 f64

    k_rowband<<<dim3(NBAND * NIMG * 2), dim3(512), 0, stream>>>(v, i_, P, bandsum);
    k_colapply<<<dim3(NBAND * NIMG * 2), dim3(576), 0, stream>>>(P, bandsum);
    k_main<<<dim3(NBLK), dim3(256), 0, stream>>>(v, i_, img, P, partials);
    k_reduce<<<dim3(1), dim3(256), 0, stream>>>(partials, NBLK, out);
}

// Round 13
// 49.452 us; speedup vs baseline: 1.7137x; 1.7137x over previous
//
#include <hip/hip_runtime.h>

#define H 512
#define W 512
#define NIMG 8
#define NBAND 32
#define BROWS 16                  // rows per band (NBAND*BROWS == H)

#define PS 576                    // padded SAT stride (PADX=31 + 513 + 32)
#define PP (PS * PS)
#define PADY 32                   // P row p = SAT row y' + 32
#define PADX 31                   // P col c = SAT col x' + 31  (keeps f4 alignment)

#define TSTR 648                  // LDS tile stride (floats) >= phi(575)+4
#define NBLK 2048                 // k_main grid size

typedef float f4 __attribute__((ext_vector_type(4), aligned(4)));
typedef float f2 __attribute__((ext_vector_type(2), aligned(4)));

__device__ __forceinline__ int phi(int c) { return c + 4 * (c >> 5); }  // bank spread

__device__ __forceinline__ f4 ld4(const float* p) {
    return *reinterpret_cast<const f4*>(p);
}

// zero-padded global load ('SAME' conv padding)
__device__ __forceinline__ float ldz(const float* __restrict__ p, int y, int x) {
    return ((unsigned)y < (unsigned)H && (unsigned)x < (unsigned)W) ? p[y * W + x] : 0.0f;
}

// load window [x0-1, x0+8] of row `row` (zero-padded), x0 = 8*lane
__device__ __forceinline__ void loadrow(const float* __restrict__ src, int row,
                                        int x0, int lane, float w[10]) {
    f4 a = {0.f, 0.f, 0.f, 0.f}, b = {0.f, 0.f, 0.f, 0.f};
    if ((unsigned)row < (unsigned)H) {
        const float* p = src + (size_t)row * W + x0;
        a = ld4(p);
        b = ld4(p + 4);
    }
    float left = __shfl_up(b[3], 1, 64);
    if (lane == 0) left = 0.f;
    float right = __shfl_down(a[0], 1, 64);
    if (lane == 63) right = 0.f;
    w[0] = left;
    w[1] = a[0]; w[2] = a[1]; w[3] = a[2]; w[4] = a[3];
    w[5] = b[0]; w[6] = b[1]; w[7] = b[2]; w[8] = b[3];
    w[9] = right;
}

// ---- kernel 1: energy + row prefix -> padded P rows + per-band col sums --
__global__ __launch_bounds__(512) void k_rowband(const float* __restrict__ v,
                                                 const float* __restrict__ i_,
                                                 float* __restrict__ P,
                                                 float* __restrict__ bandsum) {
    const int bid = blockIdx.x;
    const int n = bid & 7;
    const int t = bid >> 3;
    const int m = t & 1;
    const int b = t >> 1;                      // 0..31
    const int map = n * 2 + m;
    const float* src = (m == 0 ? v : i_) + (size_t)n * (H * W);
    float* Pm = P + (size_t)map * PP;

    __shared__ float tile[BROWS][TSTR];        // 41.5 KB

    const int tid = threadIdx.x;
    const int lane = tid & 63, wv = tid >> 6;  // wv 0..7
    const int x0 = lane * 8;

    // band-0 blocks also zero P rows 0..32 (top pad + SAT row 0)
    if (b == 0) {
        const f4 z = {0.f, 0.f, 0.f, 0.f};
        for (int s = tid; s < 33 * (PS / 4); s += 512) {
            int j = s / (PS / 4), c4 = s - j * (PS / 4);
            *reinterpret_cast<f4*>(Pm + (size_t)j * PS + 4 * c4) = z;
        }
    }

    #pragma unroll
    for (int k = 0; k < 2; ++k) {
        const int j = k * 8 + wv;              // row within band, 0..15
        const int y = b * BROWS + j;           // image row
        float w0[10], w1[10], w2[10];
        loadrow(src, y - 1, x0, lane, w0);
        loadrow(src, y,     x0, lane, w1);
        loadrow(src, y + 1, x0, lane, w2);
        float e[8];
        #pragma unroll
        for (int q = 0; q < 8; ++q) {
            float gx = (w0[q + 2] - w0[q]) + 2.0f * (w1[q + 2] - w1[q]) + (w2[q + 2] - w2[q]);
            float gy = (w2[q] - w0[q]) + 2.0f * (w2[q + 1] - w0[q + 1]) + (w2[q + 2] - w0[q + 2]);
            e[q] = gx * gx + gy * gy;
        }
        #pragma unroll
        for (int q = 1; q < 8; ++q) e[q] += e[q - 1];   // in-lane prefix
        const float tot = e[7];
        float s = tot;                                   // wave scan of lane totals
        #pragma unroll
        for (int off = 1; off < 64; off <<= 1) {
            float t2 = __shfl_up(s, off, 64);
            if (lane >= off) s += t2;
        }
        const float excl = s - tot;
        const int pc = phi(32 + x0);           // contiguous for q=0..7 (within 32-block)
        #pragma unroll
        for (int q = 0; q < 8; ++q) tile[j][pc + q] = e[q] + excl;
    }
    __syncthreads();

    // pads in LDS: left cols 0..31 = 0 (SAT col <= 0); right cols 544..575 = col 543
    {
        const int j = tid >> 5, c = tid & 31;  // 16 rows x 32 cols = 512 threads
        tile[j][phi(c)] = 0.f;
        tile[j][phi(544 + c)] = tile[j][phi(543)];
    }
    __syncthreads();

    // per-band column sums (incl. pad cols) for the column-accumulate pass
    float* bs = bandsum + ((size_t)map * NBAND + b) * PS;
    for (int c = tid; c < PS; c += 512) {
        float s = 0.f;
        #pragma unroll
        for (int j = 0; j < BROWS; ++j) s += tile[j][phi(c)];
        bs[c] = s;
    }

    // coalesced padded row-prefix writeout: P rows 33+16b .. 48+16b
    for (int s4 = tid; s4 < BROWS * (PS / 4); s4 += 512) {
        int j = s4 / (PS / 4), c4 = s4 - j * (PS / 4);
        f4 val = *reinterpret_cast<const f4*>(&tile[j][phi(4 * c4)]);
        *reinterpret_cast<f4*>(Pm + (size_t)(PADY + 1 + b * BROWS + j) * PS + 4 * c4) = val;
    }
}

// ---- kernel 2: in-place column accumulate on P (band offsets inline) -----
// Left-pad cols 0..30 are zero in row-prefix form and stay zero under
// accumulation -> skip them entirely.
__global__ __launch_bounds__(576) void k_colapply(float* __restrict__ P,
                                                  const float* __restrict__ bandsum) {
    const int bid = blockIdx.x;
    const int n = bid & 7;
    const int t = bid >> 3;
    const int m = t & 1;
    const int b = t >> 1;
    const int map = n * 2 + m;
    const int c = threadIdx.x;                 // 0..575 (one P column)
    if (c < PADX) return;                      // left pad: already zero
    const float* bs = bandsum + (size_t)map * NBAND * PS + c;
    float run = 0.f;
    for (int bb = 0; bb < b; ++bb) run += bs[(size_t)bb * PS];
    float* Pr = P + (size_t)map * PP + (size_t)(PADY + 1 + b * BROWS) * PS + c;
    #pragma unroll
    for (int j = 0; j < BROWS; ++j) {
        run += Pr[(size_t)j * PS];
        Pr[(size_t)j * PS] = run;
    }
    if (b == NBAND - 1) {                      // bottom pad rows 545..575 = SAT row 512
        float* Pp = P + (size_t)map * PP + (size_t)(PADY + 1 + H) * PS + c;
        #pragma unroll
        for (int j = 0; j < PS - (PADY + 1 + H); ++j)
            Pp[(size_t)j * PS] = run;
    }
}

// ---- sobel for 4 consecutive pixels (vectorized fast path) ---------------
__device__ __forceinline__ void sobel4(const float* __restrict__ p, int y, int x4,
                                       bool fast, float gx[4], float gy[4]) {
    float r0[6], r1[6], r2[6];
    if (fast) {
        const float* a = p + (size_t)(y - 1) * W + (x4 - 1);
        f4 A = ld4(a);             f2 Ab = *reinterpret_cast<const f2*>(a + 4);
        f4 Bv = ld4(a + W);        f2 Bb = *reinterpret_cast<const f2*>(a + W + 4);
        f4 Cv = ld4(a + 2 * W);    f2 Cb = *reinterpret_cast<const f2*>(a + 2 * W + 4);
        r0[0]=A[0];  r0[1]=A[1];  r0[2]=A[2];  r0[3]=A[3];  r0[4]=Ab[0]; r0[5]=Ab[1];
        r1[0]=Bv[0]; r1[1]=Bv[1]; r1[2]=Bv[2]; r1[3]=Bv[3]; r1[4]=Bb[0]; r1[5]=Bb[1];
        r2[0]=Cv[0]; r2[1]=Cv[1]; r2[2]=Cv[2]; r2[3]=Cv[3]; r2[4]=Cb[0]; r2[5]=Cb[1];
    } else {
        #pragma unroll
        for (int q = 0; q < 6; ++q) {
            r0[q] = ldz(p, y - 1, x4 - 1 + q);
            r1[q] = ldz(p, y,     x4 - 1 + q);
            r2[q] = ldz(p, y + 1, x4 - 1 + q);
        }
    }
    #pragma unroll
    for (int q = 0; q < 4; ++q) {
        gx[q] = (r0[q + 2] - r0[q]) + 2.0f * (r1[q + 2] - r1[q]) + (r2[q + 2] - r2[q]);
        gy[q] = (r2[q] - r0[q]) + 2.0f * (r2[q + 1] - r0[q + 1]) + (r2[q + 2] - r0[q + 2]);
    }
}

// ---- kernel 3: fused sobel + clamp-free f4 SAT gather + residual ---------
__global__ __launch_bounds__(256) void k_main(const float* __restrict__ v,
                                              const float* __restrict__ i_,
                                              const float* __restrict__ img,
                                              const float* __restrict__ P,
                                              double* __restrict__ partials) {
    const int bid = blockIdx.x;
    const int n = bid & 7;                     // image -> XCD pin
    const int t = bid >> 3;                    // 0..255
    const int tx = t & 3, ty = t >> 2;         // tile: 128 wide x 8 rows
    const int col = threadIdx.x & 31, row = threadIdx.x >> 5;
    const int x4 = tx * 128 + col * 4;
    const int y  = ty * 8 + row;

    const float* pv = v   + (size_t)n * (H * W);
    const float* pi = i_  + (size_t)n * (H * W);
    const float* pf = img + (size_t)n * (H * W);
    const float* Pv = P + (size_t)(n * 2 + 0) * PP;
    const float* Pi = P + (size_t)(n * 2 + 1) * PP;

    float gvx[4], gvy[4], gix[4], giy[4], gfx[4], gfy[4];
    const bool fast = (y >= 1 && y <= H - 2 && x4 >= 4 && x4 <= W - 8);
    sobel4(pv, y, x4, fast, gvx, gvy);
    sobel4(pi, y, x4, fast, gix, giy);
    sobel4(pf, y, x4, fast, gfx, gfy);

    float dvx[4], dvy[4], rx[4], ry[4];
    #pragma unroll
    for (int q = 0; q < 4; ++q) {
        dvx[q] = gvx[q] - gix[q];
        dvy[q] = gvy[q] - giy[q];
        rx[q]  = gfx[q] - gix[q];
        ry[q]  = gfy[q] - giy[q];
    }

    const int   radii[5] = {1, 3, 7, 15, 30};
    // wt = sv / (sv + si + eps*w^2)  (identical algebra to reference)
    const float epsw[5]  = {9e-8f, 4.9e-7f, 2.25e-6f, 9.61e-6f, 3.721e-5f};

    float acc = 0.0f;
    #pragma unroll
    for (int k = 0; k < 5; ++k) {
        const int r = radii[k];
        const size_t ro0 = (size_t)(y - r + PADY) * PS;
        const size_t ro1 = (size_t)(y + r + 1 + PADY) * PS;
        const int x0 = x4 - r + PADX;
        const int x1 = x4 + r + 1 + PADX;
        f4 sa = ld4(Pv + ro1 + x1), sb = ld4(Pv + ro0 + x1);
        f4 sc = ld4(Pv + ro1 + x0), sd = ld4(Pv + ro0 + x0);
        f4 ua = ld4(Pi + ro1 + x1), ub = ld4(Pi + ro0 + x1);
        f4 uc = ld4(Pi + ro1 + x0), ud = ld4(Pi + ro0 + x0);
        f4 sv = sa - sb - sc + sd;
        f4 si = ua - ub - uc + ud;
        #pragma unroll
        for (int q = 0; q < 4; ++q) {
            float d  = sv[q] + si[q] + epsw[k];
            float wt = sv[q] * __builtin_amdgcn_rcpf(d);
            float dx = rx[q] - wt * dvx[q];
            float dy = ry[q] - wt * dvy[q];
            acc += dx * dx + dy * dy;
        }
    }

    // block reduction (f64, deterministic)
    double a = (double)acc;
    const int lane = threadIdx.x & 63, wid = threadIdx.x >> 6;
    #pragma unroll
    for (int off = 32; off > 0; off >>= 1) a += __shfl_down(a, off, 64);
    __shared__ double red[4];
    if (lane == 0) red[wid] = a;
    __syncthreads();
    if (threadIdx.x == 0)
        partials[bid] = red[0] + red[1] + red[2] + red[3];
}

// ---- kernel 4: final reduce ----------------------------------------------
__global__ __launch_bounds__(256) void k_reduce(const double* __restrict__ partials,
                                                int np, float* __restrict__ out) {
    __shared__ double red[256];
    double s = 0.0;
    for (int idx = threadIdx.x; idx < np; idx += 256) s += partials[idx];
    red[threadIdx.x] = s;
    __syncthreads();
    #pragma unroll
    for (int t = 128; t > 0; t >>= 1) {
        if (threadIdx.x < t) red[threadIdx.x] += red[threadIdx.x + t];
        __syncthreads();
    }
    if (threadIdx.x == 0)
        out[0] = (float)(red[0] / (double)((size_t)NIMG * H * W));
}

// ---- launch --------------------------------------------------------------

extern "C" void kernel_launch(void* const* d_in, const int* in_sizes, int n_in,
                              void* d_out, int out_size, void* d_ws, size_t ws_size,
                              hipStream_t stream) {
    const float* v   = (const float*)d_in[0];
    const float* i_  = (const float*)d_in[1];
    const float* img = (const float*)d_in[2];
    float* out = (float*)d_out;

    float* P         = (float*)d_ws;                               // 16 * 576*576 f32 = 21.2 MB
    float* bandsum   = P + (size_t)16 * PP;                        // 16 * 32 * 576 f32 = 1.2 MB
    double* partials = (double*)(bandsum + (size_t)16 * NBAND * PS);  // 2048 f64

    k_rowband<<<dim3(NBAND * NIMG * 2), dim3(512), 0, stream>>>(v, i_, P, bandsum);
    k_colapply<<<dim3(NBAND * NIMG * 2), dim3(576), 0, stream>>>(P, bandsum);
    k_main<<<dim3(NBLK), dim3(256), 0, stream>>>(v, i_, img, P, partials);
    k_reduce<<<dim3(1), dim3(256), 0, stream>>>(partials, NBLK, out);
}